// Round 12
// baseline (237.949 us; speedup 1.0000x reference)
//
#include <hip/hip_runtime.h>
#include <hip/hip_bf16.h>

// Problem constants: B=2, S=2048, D=1024, H=16, HD=64
#define B_  2
#define S_  2048
#define D_  1024
#define H_  16
#define HD_ 64

using bf16x8  = __attribute__((ext_vector_type(8))) __bf16;
using floatx4 = __attribute__((ext_vector_type(4))) float;
using intx4   = __attribute__((ext_vector_type(4))) int;

__device__ __forceinline__ unsigned short f2bf(float f) {
  union { float f; unsigned int i; } v; v.f = f;
  unsigned int r = v.i + 0x7fffu + ((v.i >> 16) & 1u);   // RNE
  return (unsigned short)(r >> 16);
}
// packed f32x2 -> bf16x2: single v_cvt_pk_bf16_f32 (header fallback is ~10 ops)
__device__ __forceinline__ unsigned int f2bf_pk(float a, float b) {
  unsigned int r;
  asm("v_cvt_pk_bf16_f32 %0, %1, %2" : "=v"(r) : "v"(a), "v"(b));
  return r;
}
__device__ __forceinline__ floatx4 mfma16(bf16x8 a, bf16x8 b, floatx4 c) {
  return __builtin_amdgcn_mfma_f32_16x16x32_bf16(a, b, c, 0, 0, 0);
}
// async global->LDS, 16B/lane; LDS dest = wave-uniform base + lane*16
__device__ __forceinline__ void gld16(const unsigned short* g, unsigned short* l) {
  __builtin_amdgcn_global_load_lds(
      (const __attribute__((address_space(1))) unsigned int*)g,
      (__attribute__((address_space(3))) unsigned int*)l, 16, 0, 0);
}
// native exp2 (scores are pre-scaled by log2e in GEMM1's qscale)
#if __has_builtin(__builtin_amdgcn_exp2f)
#define EXP2(x) __builtin_amdgcn_exp2f(x)
#else
#define EXP2(x) __expf((x) * 0.6931471805599453f)
#endif
// single-bit sign-extended extract: 0 or -1
#if __has_builtin(__builtin_amdgcn_sbfe)
#define SBFE1(x, o) __builtin_amdgcn_sbfe((int)(x), (o), 1)
#else
#define SBFE1(x, o) (((int)((x) << (31 - (o)))) >> 31)
#endif
// swizzles: ushort offset of 8-ushort group within a row
#define SW8(row, g) ((((g) ^ ((row) & 7)) * 8))          // 64-ushort rows
#define SW4(row, g) ((((g) ^ (((row) >> 1) & 3)) * 8))   // 32-ushort rows
// K-row permutation: LDS row r holds token TAU(r); bits (b5,b4,b3,b2,b1,b0) ->
// (b5,b3,b2,b4,b1,b0). Makes swapped-QK^T score layout == PV A-frag layout.
#define TAU(r) (((r) & 0x23) | (((r) & 0x08) << 1) | (((r) & 0x04) << 1) | (((r) & 0x10) >> 2))

// 0.125 (1/sqrt(HD)) * log2(e): folded so attn uses raw v_exp_f32 (exp2)
#define QSCALE 0.18033688011f

// ---------------------------------------------------------------------------
// prepA: bulk fp32->bf16 converts (x, w_in[0:2048], w_out) — gemm1/gemm2
// weight inputs, must precede mid.
// ---------------------------------------------------------------------------
__global__ __launch_bounds__(256) void prepA_kernel(
    const float* __restrict__ x, const float* __restrict__ w_in,
    const float* __restrict__ w_out,
    unsigned short* __restrict__ xb, unsigned short* __restrict__ wb,
    unsigned short* __restrict__ wob)
{
  const int bid = blockIdx.x, tid = threadIdx.x;
  const float* src; unsigned short* dst; int base;
  if (bid < 2048)      { src = x;     dst = xb;  base = bid; }
  else if (bid < 3072) { src = w_in;  dst = wb;  base = bid - 2048; }
  else                 { src = w_out; dst = wob; base = bid - 3072; }
  const int i = (base * 256 + tid) * 8;
  float4 a = *(const float4*)(src + i);
  float4 b = *(const float4*)(src + i + 4);
  union { unsigned int w[4]; intx4 v; } o;
  o.w[0] = f2bf_pk(a.x, a.y); o.w[1] = f2bf_pk(a.z, a.w);
  o.w[2] = f2bf_pk(b.x, b.y); o.w[3] = f2bf_pk(b.z, b.w);
  *(intx4*)(dst + i) = o.v;
}

// ---------------------------------------------------------------------------
// mid: gemm1 (64x128 BK=32 dbuf, R9 body) FUSED with mask bit-pack and V
// transpose. R12 placement fix vs R10: role derives from s = idx>>3 (slow
// index), so HW XCD = idx&7 is role-independent — every XCD gets exactly
// 128 gemm + 64 mask + 128 vt blocks, interleaved in time (role = s%5,
// ratio 2:1:2; 320 = 5*64 per XCD). Streaming roles use VMEM BW the
// latency-bound gemm blocks leave idle.
// Mask pack: float4 loads + 4 ballots -> 4 words/wave-group. Bit layout is
// PERMUTED: stored bit beta(t) = 16*(t&3) + (t>>2); attn extracts with
// matching compile-time offsets (same op count).
// ---------------------------------------------------------------------------
__global__ __launch_bounds__(256) void mid_kernel(
    const unsigned short* __restrict__ A,      // xb
    const unsigned short* __restrict__ Bm,     // wb
    const float* __restrict__ bias,            // b_in
    unsigned short* __restrict__ Cb,           // qk
    const float* __restrict__ V, const float* __restrict__ Mm,
    unsigned short* __restrict__ vt, unsigned long long* __restrict__ mpk)
{
  __shared__ unsigned short sh[12288];          // 24KB, aliased per role
  const int idx = blockIdx.x, tid = threadIdx.x;
  const int xcd = idx & 7, s = idx >> 3;        // s in [0,320)
  const int r5 = s % 5, u = s / 5;              // u in [0,64)

  if (r5 < 2) {
    // ---- gemm1: C = A @ Bm^T + bias, BM=64 BN=128 BK=32, dbuf ----
    constexpr int MT = 2, NT = 4;
    const int N = 2048, K = 1024;
    unsigned short* As = sh;                    // [2][64*32]  = 8KB
    unsigned short* Bs = sh + 4096;             // [2][128*32] = 16KB

    const int wave = tid >> 6, lane = tid & 63;
    const int quad = lane >> 4, l15 = lane & 15;
    const int wr = wave >> 1, wc = wave & 1;
    const int g_local = u * 2 + r5;             // 0..127 within this XCD
    const int bxt = (xcd & 1) * 8 + (g_local & 7);
    const int byt = (xcd >> 1) * 16 + (g_local >> 3);
    const int bm = byt * 64, bn = bxt * 128;
    const int srow = tid >> 2, gs = tid & 3;

    auto stage = [&](int buf, int k0) {
      gld16(&A[(size_t)(bm + srow) * K + k0 + SW4(srow, gs)],
            &As[buf * 2048 + wave * 512]);
#pragma unroll
      for (int r = 0; r < 2; ++r) {
        const int row = srow + r * 64;
        gld16(&Bm[(size_t)(bn + row) * K + k0 + SW4(row, gs)],
              &Bs[buf * 4096 + wave * 512 + r * 2048]);
      }
    };

    floatx4 acc[MT][NT];
#pragma unroll
    for (int mt = 0; mt < MT; ++mt)
#pragma unroll
      for (int nt = 0; nt < NT; ++nt)
        acc[mt][nt] = (floatx4){0.f, 0.f, 0.f, 0.f};

    stage(0, 0);
    const int KSTEPS = K / 32;
    for (int ks = 0; ks < KSTEPS; ++ks) {
      const int cur = ks & 1, nxt = cur ^ 1;
      asm volatile("s_waitcnt vmcnt(0)" ::: "memory");
      __syncthreads();
      if (ks + 1 < KSTEPS) stage(nxt, (ks + 1) * 32);

      bf16x8 af[MT], bf[NT];
#pragma unroll
      for (int mt = 0; mt < MT; ++mt) {
        const int row = wr * 32 + mt * 16 + l15;
        af[mt] = *(const bf16x8*)&As[cur * 2048 + row * 32 + SW4(row, quad)];
      }
#pragma unroll
      for (int nt = 0; nt < NT; ++nt) {
        const int row = wc * 64 + nt * 16 + l15;
        bf[nt] = *(const bf16x8*)&Bs[cur * 4096 + row * 32 + SW4(row, quad)];
      }
      __builtin_amdgcn_s_setprio(1);
#pragma unroll
      for (int mt = 0; mt < MT; ++mt)
#pragma unroll
        for (int nt = 0; nt < NT; ++nt)
          acc[mt][nt] = mfma16(af[mt], bf[nt], acc[mt][nt]);
      __builtin_amdgcn_s_setprio(0);
    }

#pragma unroll
    for (int nt = 0; nt < NT; ++nt) {
      const int col = bn + wc * 64 + nt * 16 + l15;
      const float bi = bias[col];
      const float sc = (col < 1024) ? QSCALE : 1.0f;
#pragma unroll
      for (int mt = 0; mt < MT; ++mt) {
        const int row0 = bm + wr * 32 + mt * 16 + quad * 4;
#pragma unroll
        for (int reg = 0; reg < 4; ++reg)
          Cb[(size_t)(row0 + reg) * N + col] = f2bf((acc[mt][nt][reg] + bi) * sc);
      }
    }
  } else if (r5 == 2) {
    // ---- mask bit-pack, float4 + ballot: 256 words (16384 floats)/block ----
    // stored word bit beta = 16*(t&3) + (t>>2), t = float within word.
    const int m_local = xcd * 64 + u;            // 0..511
    const int wv = tid >> 6, lane = tid & 63;
#pragma unroll 4
    for (int it = 0; it < 16; ++it) {
      const size_t g = (size_t)m_local * 64 + it * 4 + wv;  // 256-float group
      float4 m4 = *(const float4*)(Mm + g * 256 + lane * 4);
      unsigned long long b0 = __ballot(m4.x != 0.0f);
      unsigned long long b1 = __ballot(m4.y != 0.0f);
      unsigned long long b2 = __ballot(m4.z != 0.0f);
      unsigned long long b3 = __ballot(m4.w != 0.0f);
      if (lane < 4) {
        const int sh16 = lane * 16;
        unsigned long long w =  ((b0 >> sh16) & 0xFFFFull)
                             | (((b1 >> sh16) & 0xFFFFull) << 16)
                             | (((b2 >> sh16) & 0xFFFFull) << 32)
                             | (((b3 >> sh16) & 0xFFFFull) << 48);
        mpk[g * 4 + lane] = w;
      }
    }
  } else {
    // ---- V transpose (b,h,64-token tile) -> vt [B][H][HD][S] ----
    const int vidx = xcd * 128 + u * 2 + (r5 - 3);      // 0..1023
    const int t0 = (vidx & 31) * 64, h = (vidx >> 5) & 15, b = vidx >> 9;
    const int sr = tid >> 3, sc = (tid & 7) * 8;
    unsigned short* tile = sh;                          // 64*72 ush = 9KB
    const float* src = V + ((size_t)((b * S_ + t0) * H_ + h)) * HD_;
#pragma unroll
    for (int half = 0; half < 2; ++half) {
      const int r = sr + half * 32;
      float4 v0 = *(const float4*)&src[(size_t)r * (H_ * HD_) + sc];
      float4 v1 = *(const float4*)&src[(size_t)r * (H_ * HD_) + sc + 4];
      union { unsigned int w[4]; intx4 v; } p;
      p.w[0] = f2bf_pk(v0.x, v0.y); p.w[1] = f2bf_pk(v0.z, v0.w);
      p.w[2] = f2bf_pk(v1.x, v1.y); p.w[3] = f2bf_pk(v1.z, v1.w);
      *(intx4*)&tile[r * 72 + sc] = p.v;
    }
    __syncthreads();
    unsigned short* dst = vt + ((size_t)((b * H_ + h) * HD_)) * S_ + t0;
    union { unsigned short u8[8]; intx4 v; } pack;
#pragma unroll
    for (int j2 = 0; j2 < 8; ++j2) pack.u8[j2] = tile[(sc + j2) * 72 + sr];
    *(intx4*)&dst[(size_t)sr * S_ + sc] = pack.v;
#pragma unroll
    for (int j2 = 0; j2 < 8; ++j2) pack.u8[j2] = tile[(sc + j2) * 72 + sr + 32];
    *(intx4*)&dst[(size_t)(sr + 32) * S_ + sc] = pack.v;
  }
}

// ---------------------------------------------------------------------------
// bf16 MFMA GEMM (gemm2), 64x64 BK=32, dbuf, XCD-swizzled 1D grid — R9 body.
// ---------------------------------------------------------------------------
template<int BM, int BN>
__global__ __launch_bounds__(256) void gemm_tile(
    const unsigned short* __restrict__ A,
    const unsigned short* __restrict__ Bm,
    const float* __restrict__ bias,
    unsigned short* __restrict__ Cb, float* __restrict__ Cf,
    int N, int K, int qscale)
{
  constexpr int MT = BM / 32;
  constexpr int NT = BN / 32;
  __shared__ unsigned short As[2][BM * 32];
  __shared__ unsigned short Bs[2][BN * 32];

  const int tid  = threadIdx.x;
  const int wave = tid >> 6, lane = tid & 63;
  const int quad = lane >> 4, l15 = lane & 15;
  const int wr = wave >> 1, wc = wave & 1;
  const int L = blockIdx.x;
  const int xcd = L & 7, j = L >> 3;
  const int bxt = (xcd & 1) * 8 + (j & 7);
  const int byt = (xcd >> 1) * 16 + (j >> 3);
  const int bm = byt * BM, bn = bxt * BN;
  const int srow = tid >> 2, gs = tid & 3;

  auto stage = [&](int buf, int k0) {
#pragma unroll
    for (int r = 0; r < BM / 64; ++r) {
      const int row = srow + r * 64;
      gld16(&A[(size_t)(bm + row) * K + k0 + SW4(row, gs)],
            &As[buf][wave * 512 + r * 2048]);
    }
#pragma unroll
    for (int r = 0; r < BN / 64; ++r) {
      const int row = srow + r * 64;
      gld16(&Bm[(size_t)(bn + row) * K + k0 + SW4(row, gs)],
            &Bs[buf][wave * 512 + r * 2048]);
    }
  };

  floatx4 acc[MT][NT];
#pragma unroll
  for (int mt = 0; mt < MT; ++mt)
#pragma unroll
    for (int nt = 0; nt < NT; ++nt)
      acc[mt][nt] = (floatx4){0.f, 0.f, 0.f, 0.f};

  stage(0, 0);

  const int KSTEPS = K / 32;
  for (int ks = 0; ks < KSTEPS; ++ks) {
    const int cur = ks & 1, nxt = cur ^ 1;
    asm volatile("s_waitcnt vmcnt(0)" ::: "memory");
    __syncthreads();
    if (ks + 1 < KSTEPS) stage(nxt, (ks + 1) * 32);

    bf16x8 af[MT], bf[NT];
#pragma unroll
    for (int mt = 0; mt < MT; ++mt) {
      const int row = wr * (BM / 2) + mt * 16 + l15;
      af[mt] = *(const bf16x8*)&As[cur][row * 32 + SW4(row, quad)];
    }
#pragma unroll
    for (int nt = 0; nt < NT; ++nt) {
      const int row = wc * (BN / 2) + nt * 16 + l15;
      bf[nt] = *(const bf16x8*)&Bs[cur][row * 32 + SW4(row, quad)];
    }
    __builtin_amdgcn_s_setprio(1);
#pragma unroll
    for (int mt = 0; mt < MT; ++mt)
#pragma unroll
      for (int nt = 0; nt < NT; ++nt)
        acc[mt][nt] = mfma16(af[mt], bf[nt], acc[mt][nt]);
    __builtin_amdgcn_s_setprio(0);
  }

#pragma unroll
  for (int nt = 0; nt < NT; ++nt) {
    const int col = bn + wc * (BN / 2) + nt * 16 + l15;
    const float bi = bias[col];
    const float sc = (qscale && col < 1024) ? QSCALE : 1.0f;
#pragma unroll
    for (int mt = 0; mt < MT; ++mt) {
      const int row0 = bm + wr * (BM / 2) + mt * 16 + quad * 4;
#pragma unroll
      for (int reg = 0; reg < 4; ++reg) {
        const float v = (acc[mt][nt][reg] + bi) * sc;
        if (Cf) Cf[(size_t)(row0 + reg) * N + col] = v;
        else    Cb[(size_t)(row0 + reg) * N + col] = f2bf(v);
      }
    }
  }
}

// ---------------------------------------------------------------------------
// Fused masked-renorm attention: out = sum(e*M*V)/sum(e*M).
// R12 = R9 structure; ONLY change: mask bit extraction matches the new
// permuted layout beta(t) = 16*(t&3) + (t>>2). Pre-shift by 2*quad, then
// offset 16*(reg&1) + 8*(nt>>1) + (nt&1) on the reg-selected 32-bit half
// (verified: t = 32h+8q+4a+r -> beta = 16r+8h+2q+a). Same op count.
// ---------------------------------------------------------------------------
__global__ __launch_bounds__(256) void attn_kernel(
    const unsigned short* __restrict__ QK,      // [B*S][2048]
    const unsigned short* __restrict__ Vt,      // [B][H][HD][S]
    const unsigned long long* __restrict__ Mpk, // [B*S][S/64], permuted bits
    unsigned short* __restrict__ ctx)           // [B*S][D]
{
  __shared__ unsigned short Ks[2][64 * 64];
  __shared__ unsigned short Vs[2][64 * 64];
  __shared__ unsigned long long Ms64[2][64];

  const int tid  = threadIdx.x;
  const int wave = tid >> 6, lane = tid & 63;
  const int quad = lane >> 4, l15 = lane & 15;
  const int L = blockIdx.x;
  const int xcd = L & 7, j = L >> 3;
  const int pair = ((j >> 5) << 3) + xcd;      // 0..31
  const int b = pair >> 4, h = pair & 15;
  const int qb = (j & 31) * 64;
  const int gs = tid & 7;

  const unsigned short* Qbase = QK + (size_t)(b * S_ + qb) * 2048 + h * HD_;
  const unsigned short* Kbase = QK + (size_t)(b * S_) * 2048 + D_ + h * HD_;
  const unsigned short* Vbase = Vt + (size_t)((b * H_ + h) * HD_) * S_;
  const unsigned long long* Mbase = Mpk + (size_t)(b * S_ + qb) * (S_ / 64);

  // ---- stage Q (64x64, stride 64) into the Ks[0] region ----
  unsigned short* Qs = &Ks[0][0];
#pragma unroll
  for (int r = 0; r < 2; ++r) {
    const int row = (tid >> 3) + r * 32;
    gld16(Qbase + (size_t)row * 2048 + SW8(row, gs), Qs + wave * 512 + r * 2048);
  }
  if (tid < 64) Ms64[0][tid] = Mbase[(size_t)tid * (S_ / 64)];
  asm volatile("s_waitcnt vmcnt(0)" ::: "memory");
  __syncthreads();

  // loop-invariant Q fragments (rows wave*16..+15)
  bf16x8 qf[2];
#pragma unroll
  for (int c = 0; c < 2; ++c) {
    const int row = wave * 16 + l15;
    qf[c] = *(const bf16x8*)&Qs[row * 64 + SW8(row, c * 4 + quad)];
  }
  __syncthreads();   // all qf reads done before K tile-0 staging overwrites

  // ---- stage tile 0 K (TAU-permuted rows) and V ----
#pragma unroll
  for (int r = 0; r < 2; ++r) {
    const int rowd = (tid >> 3) + r * 32;
    const int tokK = TAU(rowd);
    gld16(Kbase + (size_t)tokK * 2048 + SW8(rowd, gs), &Ks[0][wave * 512 + r * 2048]);
    gld16(Vbase + (size_t)rowd * S_ + SW8(rowd, gs),   &Vs[0][wave * 512 + r * 2048]);
  }

  floatx4 accO[4];
  float Pp = 0.f;
#pragma unroll
  for (int nt = 0; nt < 4; ++nt)
    accO[nt] = (floatx4){0.f, 0.f, 0.f, 0.f};

  const int q2 = quad * 2;

  for (int i = 0; i < 32; ++i) {
    const int cur = i & 1, nxt = cur ^ 1;
    asm volatile("s_waitcnt vmcnt(0)" ::: "memory");  // buf[cur] staged
    __syncthreads();  // all waves done with buf[nxt] (tile i-1)

    if (i + 1 < 32) {  // prefetch tile i+1
      const int t1 = (i + 1) * 64;
#pragma unroll
      for (int r = 0; r < 2; ++r) {
        const int rowd = (tid >> 3) + r * 32;
        const int tokK = TAU(rowd);
        gld16(Kbase + (size_t)(t1 + tokK) * 2048 + SW8(rowd, gs),
              &Ks[nxt][wave * 512 + r * 2048]);
        gld16(Vbase + (size_t)rowd * S_ + t1 + SW8(rowd, gs),
              &Vs[nxt][wave * 512 + r * 2048]);
      }
      if (tid < 64)
        Ms64[nxt][tid] = Mbase[(size_t)tid * (S_ / 64) + i + 1];
    }

    // S^T = K @ Q^T (swapped operands): lane l15 = q-row, quad/reg = token
    floatx4 sc[4];
    __builtin_amdgcn_s_setprio(1);
#pragma unroll
    for (int nt = 0; nt < 4; ++nt) {
      const int row = nt * 16 + l15;
      bf16x8 kf0 = *(const bf16x8*)&Ks[cur][row * 64 + SW8(row, quad)];
      bf16x8 kf1 = *(const bf16x8*)&Ks[cur][row * 64 + SW8(row, 4 + quad)];
      floatx4 z = (floatx4){0.f, 0.f, 0.f, 0.f};
      z = mfma16(kf0, qf[0], z);
      z = mfma16(kf1, qf[1], z);
      sc[nt] = z;
    }
    __builtin_amdgcn_s_setprio(0);

    // mask word (permuted layout): pre-shift by 2*quad; halves split on reg
    const unsigned long long ms = Ms64[cur][wave * 16 + l15] >> q2;
    const unsigned int u_lo = (unsigned int)ms;
    const unsigned int u_hi = (unsigned int)(ms >> 32);

    // V fragments — independent of P, hoisted above the softmax
    bf16x8 vf0[4], vf1[4];
#pragma unroll
    for (int nt = 0; nt < 4; ++nt) {
      const int row = nt * 16 + l15;
      vf0[nt] = *(const bf16x8*)&Vs[cur][row * 64 + SW8(row, quad)];
      vf1[nt] = *(const bf16x8*)&Vs[cur][row * 64 + SW8(row, 4 + quad)];
    }

    // softmax: exp2 + sbfe/and mask, pack straight into PV A-frags
    bf16x8 pa0, pa1;
    {
      union { unsigned int w[4]; bf16x8 v; } A0, A1;
#pragma unroll
      for (int nt = 0; nt < 4; ++nt) {
        float p[4];
#pragma unroll
        for (int reg = 0; reg < 4; ++reg) {
          const unsigned int ws = (reg < 2) ? u_lo : u_hi;
          const int off = 16 * (reg & 1) + 8 * (nt >> 1) + (nt & 1);
          const float e = EXP2(sc[nt][reg]);
          const int m = SBFE1(ws, off);           // 0 or -1
          p[reg] = __uint_as_float(__float_as_uint(e) & (unsigned int)m);
        }
        Pp += (p[0] + p[1]) + (p[2] + p[3]);
        const unsigned int d0 = f2bf_pk(p[0], p[1]);
        const unsigned int d1 = f2bf_pk(p[2], p[3]);
        if (nt == 0)      { A0.w[0] = d0; A0.w[1] = d1; }
        else if (nt == 1) { A0.w[2] = d0; A0.w[3] = d1; }
        else if (nt == 2) { A1.w[0] = d0; A1.w[1] = d1; }
        else              { A1.w[2] = d0; A1.w[3] = d1; }
      }
      pa0 = A0.v; pa1 = A1.v;
    }

    // O += P @ V^T (P already in A-frag layout)
    __builtin_amdgcn_s_setprio(1);
#pragma unroll
    for (int nt = 0; nt < 4; ++nt) {
      accO[nt] = mfma16(pa0, vf0[nt], accO[nt]);
      accO[nt] = mfma16(pa1, vf1[nt], accO[nt]);
    }
    __builtin_amdgcn_s_setprio(0);
  }

  // Pp: lane (quad,l15) holds partial row-sum for q-row l15 over that quad's
  // tokens. Reduce over quads (lane^16, lane^32).
  Pp += __shfl_xor(Pp, 16);
  Pp += __shfl_xor(Pp, 32);
  Pp = 1.0f / (Pp + 1e-30f);
  // redistribute: epilogue needs inv-sum for q-row quad*4 + reg
  float Ppe[4];
#pragma unroll
  for (int reg = 0; reg < 4; ++reg)
    Ppe[reg] = __shfl(Pp, (quad << 4) | (quad * 4 + reg));

#pragma unroll
  for (int nt = 0; nt < 4; ++nt)
#pragma unroll
    for (int reg = 0; reg < 4; ++reg) {
      const int row = wave * 16 + quad * 4 + reg;
      ctx[(size_t)(b * S_ + qb + row) * D_ + h * HD_ + nt * 16 + l15] =
          f2bf(accO[nt][reg] * Ppe[reg]);
    }
}

// ---------------------------------------------------------------------------
extern "C" void kernel_launch(void* const* d_in, const int* in_sizes, int n_in,
                              void* d_out, int out_size, void* d_ws, size_t ws_size,
                              hipStream_t stream) {
  const float* x     = (const float*)d_in[0];
  const float* V     = (const float*)d_in[1];
  const float* Mm    = (const float*)d_in[2];
  const float* w_in  = (const float*)d_in[3];
  const float* b_in  = (const float*)d_in[4];
  const float* w_out = (const float*)d_in[5];
  const float* b_out = (const float*)d_in[6];
  float* out = (float*)d_out;                  // fp32 (verified R5)

  // workspace layout (ushort units)
  unsigned short* qk  = (unsigned short*)d_ws;          // 8M   [4096][2048]
  unsigned short* vt  = qk  + (size_t)8 * 1024 * 1024;  // 4M   [B][H][HD][S]
  unsigned short* ctx = vt  + (size_t)4 * 1024 * 1024;  // 4M   [4096][1024]
  unsigned short* xb  = ctx + (size_t)4 * 1024 * 1024;  // 4M   bf16(x)
  unsigned short* wb  = xb  + (size_t)4 * 1024 * 1024;  // 2M   bf16(w_in[0:2048])
  unsigned short* wob = wb  + (size_t)2 * 1024 * 1024;  // 1M   bf16(out_w)
  unsigned long long* mpk = (unsigned long long*)(wob + (size_t)1024 * 1024);

  // 1) converts (gemm inputs)
  prepA_kernel<<<3584, 256, 0, stream>>>(x, w_in, w_out, xb, wb, wob);

  // 2) gemm1 (qk, Q pre-scaled) || mask pack || V transpose — one dispatch,
  //    role from slow index so XCD placement is role-independent
  mid_kernel<<<2560, 256, 0, stream>>>(xb, wb, b_in, qk, V, Mm, vt, mpk);

  // 3) fused masked-renorm attention -> ctx (bf16), XCD-swizzled 1D grid
  attn_kernel<<<1024, 256, 0, stream>>>(qk, vt, mpk, ctx);

  // 4) out = ctx @ out_w^T + out_b  (fp32 store to d_out)
  gemm_tile<64, 64><<<1024, 256, 0, stream>>>(
      ctx, wob, b_out, nullptr, out, D_, D_, 0);
}

// Round 13
// 226.365 us; speedup vs baseline: 1.0512x; 1.0512x over previous
//
#include <hip/hip_runtime.h>
#include <hip/hip_bf16.h>

// Problem constants: B=2, S=2048, D=1024, H=16, HD=64
#define B_  2
#define S_  2048
#define D_  1024
#define H_  16
#define HD_ 64

using bf16x8  = __attribute__((ext_vector_type(8))) __bf16;
using floatx4 = __attribute__((ext_vector_type(4))) float;
using intx4   = __attribute__((ext_vector_type(4))) int;

__device__ __forceinline__ unsigned short f2bf(float f) {
  union { float f; unsigned int i; } v; v.f = f;
  unsigned int r = v.i + 0x7fffu + ((v.i >> 16) & 1u);   // RNE
  return (unsigned short)(r >> 16);
}
// packed f32x2 -> bf16x2: single v_cvt_pk_bf16_f32 (header fallback is ~10 ops)
__device__ __forceinline__ unsigned int f2bf_pk(float a, float b) {
  unsigned int r;
  asm("v_cvt_pk_bf16_f32 %0, %1, %2" : "=v"(r) : "v"(a), "v"(b));
  return r;
}
__device__ __forceinline__ floatx4 mfma16(bf16x8 a, bf16x8 b, floatx4 c) {
  return __builtin_amdgcn_mfma_f32_16x16x32_bf16(a, b, c, 0, 0, 0);
}
// async global->LDS, 16B/lane; LDS dest = wave-uniform base + lane*16
__device__ __forceinline__ void gld16(const unsigned short* g, unsigned short* l) {
  __builtin_amdgcn_global_load_lds(
      (const __attribute__((address_space(1))) unsigned int*)g,
      (__attribute__((address_space(3))) unsigned int*)l, 16, 0, 0);
}
// native exp2 (scores are pre-scaled by log2e in GEMM1's qscale)
#if __has_builtin(__builtin_amdgcn_exp2f)
#define EXP2(x) __builtin_amdgcn_exp2f(x)
#else
#define EXP2(x) __expf((x) * 0.6931471805599453f)
#endif
// single-bit sign-extended extract: 0 or -1
#if __has_builtin(__builtin_amdgcn_sbfe)
#define SBFE1(x, o) __builtin_amdgcn_sbfe((int)(x), (o), 1)
#else
#define SBFE1(x, o) (((int)((x) << (31 - (o)))) >> 31)
#endif
// swizzles: ushort offset of 8-ushort group within a row
#define SW8(row, g) ((((g) ^ ((row) & 7)) * 8))          // 64-ushort rows
#define SW4(row, g) ((((g) ^ (((row) >> 1) & 3)) * 8))   // 32-ushort rows
// K-row permutation: LDS row r holds token TAU(r); bits (b5,b4,b3,b2,b1,b0) ->
// (b5,b3,b2,b4,b1,b0). Makes swapped-QK^T score layout == PV A-frag layout.
#define TAU(r) (((r) & 0x23) | (((r) & 0x08) << 1) | (((r) & 0x04) << 1) | (((r) & 0x10) >> 2))

// 0.125 (1/sqrt(HD)) * log2(e): folded so attn uses raw v_exp_f32 (exp2)
#define QSCALE 0.18033688011f

// ---------------------------------------------------------------------------
// prep: one dispatch doing all pre-passes (R9 structure; R13: mask section
// replaced by the float4+ballot packer verified in R12).
// blocks [0,2048): cvt x | [2048,3072): cvt w_in[0:2048] | [3072,3584): cvt
// w_out | [3584,4096): mask->bitpack (ballot, permuted bit layout) |
// [4096,5120): V transpose to [B][H][HD][S]
// ---------------------------------------------------------------------------
__global__ __launch_bounds__(256) void prep_kernel(
    const float* __restrict__ x, const float* __restrict__ w_in,
    const float* __restrict__ w_out, const float* __restrict__ V,
    const float* __restrict__ Mm,
    unsigned short* __restrict__ xb, unsigned short* __restrict__ wb,
    unsigned short* __restrict__ wob, unsigned short* __restrict__ vt,
    unsigned long long* __restrict__ mpk)
{
  __shared__ unsigned short tile[64 * 72];
  const int bid = blockIdx.x, tid = threadIdx.x;

  if (bid < 3584) {                       // bulk fp32->bf16 converts
    const float* src; unsigned short* dst; int base;
    if (bid < 2048)      { src = x;     dst = xb;  base = bid; }
    else if (bid < 3072) { src = w_in;  dst = wb;  base = bid - 2048; }
    else                 { src = w_out; dst = wob; base = bid - 3072; }
    const int i = (base * 256 + tid) * 8;
    float4 a = *(const float4*)(src + i);
    float4 b = *(const float4*)(src + i + 4);
    union { unsigned int w[4]; intx4 v; } o;
    o.w[0] = f2bf_pk(a.x, a.y); o.w[1] = f2bf_pk(a.z, a.w);
    o.w[2] = f2bf_pk(b.x, b.y); o.w[3] = f2bf_pk(b.z, b.w);
    *(intx4*)(dst + i) = o.v;
  } else if (bid < 4096) {
    // ---- mask bit-pack, float4 + ballot (verified R12): 256 words/block ----
    // stored word bit beta(t) = 16*(t&3) + (t>>2), t = float within word.
    const int m_local = bid - 3584;              // 0..511
    const int wv = tid >> 6, lane = tid & 63;
#pragma unroll 4
    for (int it = 0; it < 16; ++it) {
      const size_t g = (size_t)m_local * 64 + it * 4 + wv;  // 256-float group
      float4 m4 = *(const float4*)(Mm + g * 256 + lane * 4);
      unsigned long long b0 = __ballot(m4.x != 0.0f);
      unsigned long long b1 = __ballot(m4.y != 0.0f);
      unsigned long long b2 = __ballot(m4.z != 0.0f);
      unsigned long long b3 = __ballot(m4.w != 0.0f);
      if (lane < 4) {
        const int sh16 = lane * 16;
        unsigned long long w =  ((b0 >> sh16) & 0xFFFFull)
                             | (((b1 >> sh16) & 0xFFFFull) << 16)
                             | (((b2 >> sh16) & 0xFFFFull) << 32)
                             | (((b3 >> sh16) & 0xFFFFull) << 48);
        mpk[g * 4 + lane] = w;
      }
    }
  } else {                                 // V transpose (b,h,64-token tile)
    const int idx = bid - 4096;
    const int t0 = (idx & 31) * 64, h = (idx >> 5) & 15, b = idx >> 9;
    const int sr = tid >> 3, sc = (tid & 7) * 8;
    const float* src = V + ((size_t)((b * S_ + t0) * H_ + h)) * HD_;
#pragma unroll
    for (int half = 0; half < 2; ++half) {
      const int r = sr + half * 32;
      float4 v0 = *(const float4*)&src[(size_t)r * (H_ * HD_) + sc];
      float4 v1 = *(const float4*)&src[(size_t)r * (H_ * HD_) + sc + 4];
      union { unsigned int w[4]; intx4 v; } p;
      p.w[0] = f2bf_pk(v0.x, v0.y); p.w[1] = f2bf_pk(v0.z, v0.w);
      p.w[2] = f2bf_pk(v1.x, v1.y); p.w[3] = f2bf_pk(v1.z, v1.w);
      *(intx4*)&tile[r * 72 + sc] = p.v;
    }
    __syncthreads();
    unsigned short* dst = vt + ((size_t)((b * H_ + h) * HD_)) * S_ + t0;
    union { unsigned short u[8]; intx4 v; } pack;
#pragma unroll
    for (int j = 0; j < 8; ++j) pack.u[j] = tile[(sc + j) * 72 + sr];
    *(intx4*)&dst[(size_t)sr * S_ + sc] = pack.v;
#pragma unroll
    for (int j = 0; j < 8; ++j) pack.u[j] = tile[(sc + j) * 72 + sr + 32];
    *(intx4*)&dst[(size_t)(sr + 32) * S_ + sc] = pack.v;
  }
}

// ---------------------------------------------------------------------------
// bf16 MFMA GEMM, templated tile (R9 body, verified): C = A @ Bm^T + bias.
// BK=32, wave grid 2x2, double-buffered staging, XCD-swizzled 1D grid
// (16 n-tiles x 64 m-tiles). qscale: cols<1024 *= QSCALE.
// ---------------------------------------------------------------------------
template<int BM, int BN>
__global__ __launch_bounds__(256) void gemm_tile(
    const unsigned short* __restrict__ A,
    const unsigned short* __restrict__ Bm,
    const float* __restrict__ bias,
    unsigned short* __restrict__ Cb, float* __restrict__ Cf,
    int N, int K, int qscale)
{
  constexpr int MT = BM / 32;
  constexpr int NT = BN / 32;
  __shared__ unsigned short As[2][BM * 32];
  __shared__ unsigned short Bs[2][BN * 32];

  const int tid  = threadIdx.x;
  const int wave = tid >> 6, lane = tid & 63;
  const int quad = lane >> 4, l15 = lane & 15;
  const int wr = wave >> 1, wc = wave & 1;
  const int L = blockIdx.x;
  const int xcd = L & 7, j = L >> 3;
  const int bxt = (xcd & 1) * 8 + (j & 7);
  const int byt = (xcd >> 1) * 16 + (j >> 3);
  const int bm = byt * BM, bn = bxt * BN;
  const int srow = tid >> 2, gs = tid & 3;

  auto stage = [&](int buf, int k0) {
#pragma unroll
    for (int r = 0; r < BM / 64; ++r) {
      const int row = srow + r * 64;
      gld16(&A[(size_t)(bm + row) * K + k0 + SW4(row, gs)],
            &As[buf][wave * 512 + r * 2048]);
    }
#pragma unroll
    for (int r = 0; r < BN / 64; ++r) {
      const int row = srow + r * 64;
      gld16(&Bm[(size_t)(bn + row) * K + k0 + SW4(row, gs)],
            &Bs[buf][wave * 512 + r * 2048]);
    }
  };

  floatx4 acc[MT][NT];
#pragma unroll
  for (int mt = 0; mt < MT; ++mt)
#pragma unroll
    for (int nt = 0; nt < NT; ++nt)
      acc[mt][nt] = (floatx4){0.f, 0.f, 0.f, 0.f};

  stage(0, 0);

  const int KSTEPS = K / 32;
  for (int ks = 0; ks < KSTEPS; ++ks) {
    const int cur = ks & 1, nxt = cur ^ 1;
    asm volatile("s_waitcnt vmcnt(0)" ::: "memory");
    __syncthreads();
    if (ks + 1 < KSTEPS) stage(nxt, (ks + 1) * 32);

    bf16x8 af[MT], bf[NT];
#pragma unroll
    for (int mt = 0; mt < MT; ++mt) {
      const int row = wr * (BM / 2) + mt * 16 + l15;
      af[mt] = *(const bf16x8*)&As[cur][row * 32 + SW4(row, quad)];
    }
#pragma unroll
    for (int nt = 0; nt < NT; ++nt) {
      const int row = wc * (BN / 2) + nt * 16 + l15;
      bf[nt] = *(const bf16x8*)&Bs[cur][row * 32 + SW4(row, quad)];
    }
    __builtin_amdgcn_s_setprio(1);
#pragma unroll
    for (int mt = 0; mt < MT; ++mt)
#pragma unroll
      for (int nt = 0; nt < NT; ++nt)
        acc[mt][nt] = mfma16(af[mt], bf[nt], acc[mt][nt]);
    __builtin_amdgcn_s_setprio(0);
  }

#pragma unroll
  for (int nt = 0; nt < NT; ++nt) {
    const int col = bn + wc * (BN / 2) + nt * 16 + l15;
    const float bi = bias[col];
    const float sc = (qscale && col < 1024) ? QSCALE : 1.0f;
#pragma unroll
    for (int mt = 0; mt < MT; ++mt) {
      const int row0 = bm + wr * (BM / 2) + mt * 16 + quad * 4;
#pragma unroll
      for (int reg = 0; reg < 4; ++reg) {
        const float v = (acc[mt][nt][reg] + bi) * sc;
        if (Cf) Cf[(size_t)(row0 + reg) * N + col] = v;
        else    Cb[(size_t)(row0 + reg) * N + col] = f2bf(v);
      }
    }
  }
}

// ---------------------------------------------------------------------------
// Fused masked-renorm attention: out = sum(e*M*V)/sum(e*M).
// R13 = R9 structure + R12's verified permuted-mask extraction:
// beta(t) = 16*(t&3) + (t>>2); pre-shift by 2*quad, offset
// 16*(reg&1) + 8*(nt>>1) + (nt&1) on the reg-selected half. Same op count.
// ---------------------------------------------------------------------------
__global__ __launch_bounds__(256) void attn_kernel(
    const unsigned short* __restrict__ QK,      // [B*S][2048]
    const unsigned short* __restrict__ Vt,      // [B][H][HD][S]
    const unsigned long long* __restrict__ Mpk, // [B*S][S/64], permuted bits
    unsigned short* __restrict__ ctx)           // [B*S][D]
{
  __shared__ unsigned short Ks[2][64 * 64];
  __shared__ unsigned short Vs[2][64 * 64];
  __shared__ unsigned long long Ms64[2][64];

  const int tid  = threadIdx.x;
  const int wave = tid >> 6, lane = tid & 63;
  const int quad = lane >> 4, l15 = lane & 15;
  const int L = blockIdx.x;
  const int xcd = L & 7, j = L >> 3;
  const int pair = ((j >> 5) << 3) + xcd;      // 0..31
  const int b = pair >> 4, h = pair & 15;
  const int qb = (j & 31) * 64;
  const int gs = tid & 7;

  const unsigned short* Qbase = QK + (size_t)(b * S_ + qb) * 2048 + h * HD_;
  const unsigned short* Kbase = QK + (size_t)(b * S_) * 2048 + D_ + h * HD_;
  const unsigned short* Vbase = Vt + (size_t)((b * H_ + h) * HD_) * S_;
  const unsigned long long* Mbase = Mpk + (size_t)(b * S_ + qb) * (S_ / 64);

  // ---- stage Q (64x64, stride 64) into the Ks[0] region ----
  unsigned short* Qs = &Ks[0][0];
#pragma unroll
  for (int r = 0; r < 2; ++r) {
    const int row = (tid >> 3) + r * 32;
    gld16(Qbase + (size_t)row * 2048 + SW8(row, gs), Qs + wave * 512 + r * 2048);
  }
  if (tid < 64) Ms64[0][tid] = Mbase[(size_t)tid * (S_ / 64)];
  asm volatile("s_waitcnt vmcnt(0)" ::: "memory");
  __syncthreads();

  // loop-invariant Q fragments (rows wave*16..+15)
  bf16x8 qf[2];
#pragma unroll
  for (int c = 0; c < 2; ++c) {
    const int row = wave * 16 + l15;
    qf[c] = *(const bf16x8*)&Qs[row * 64 + SW8(row, c * 4 + quad)];
  }
  __syncthreads();   // all qf reads done before K tile-0 staging overwrites

  // ---- stage tile 0 K (TAU-permuted rows) and V ----
#pragma unroll
  for (int r = 0; r < 2; ++r) {
    const int rowd = (tid >> 3) + r * 32;
    const int tokK = TAU(rowd);
    gld16(Kbase + (size_t)tokK * 2048 + SW8(rowd, gs), &Ks[0][wave * 512 + r * 2048]);
    gld16(Vbase + (size_t)rowd * S_ + SW8(rowd, gs),   &Vs[0][wave * 512 + r * 2048]);
  }

  floatx4 accO[4];
  float Pp = 0.f;
#pragma unroll
  for (int nt = 0; nt < 4; ++nt)
    accO[nt] = (floatx4){0.f, 0.f, 0.f, 0.f};

  const int q2 = quad * 2;

  for (int i = 0; i < 32; ++i) {
    const int cur = i & 1, nxt = cur ^ 1;
    asm volatile("s_waitcnt vmcnt(0)" ::: "memory");  // buf[cur] staged
    __syncthreads();  // all waves done with buf[nxt] (tile i-1)

    if (i + 1 < 32) {  // prefetch tile i+1
      const int t1 = (i + 1) * 64;
#pragma unroll
      for (int r = 0; r < 2; ++r) {
        const int rowd = (tid >> 3) + r * 32;
        const int tokK = TAU(rowd);
        gld16(Kbase + (size_t)(t1 + tokK) * 2048 + SW8(rowd, gs),
              &Ks[nxt][wave * 512 + r * 2048]);
        gld16(Vbase + (size_t)rowd * S_ + t1 + SW8(rowd, gs),
              &Vs[nxt][wave * 512 + r * 2048]);
      }
      if (tid < 64)
        Ms64[nxt][tid] = Mbase[(size_t)tid * (S_ / 64) + i + 1];
    }

    // S^T = K @ Q^T (swapped operands): lane l15 = q-row, quad/reg = token
    floatx4 sc[4];
    __builtin_amdgcn_s_setprio(1);
#pragma unroll
    for (int nt = 0; nt < 4; ++nt) {
      const int row = nt * 16 + l15;
      bf16x8 kf0 = *(const bf16x8*)&Ks[cur][row * 64 + SW8(row, quad)];
      bf16x8 kf1 = *(const bf16x8*)&Ks[cur][row * 64 + SW8(row, 4 + quad)];
      floatx4 z = (floatx4){0.f, 0.f, 0.f, 0.f};
      z = mfma16(kf0, qf[0], z);
      z = mfma16(kf1, qf[1], z);
      sc[nt] = z;
    }
    __builtin_amdgcn_s_setprio(0);

    // mask word (permuted layout): pre-shift by 2*quad; halves split on reg
    const unsigned long long ms = Ms64[cur][wave * 16 + l15] >> q2;
    const unsigned int u_lo = (unsigned int)ms;
    const unsigned int u_hi = (unsigned int)(ms >> 32);

    // V fragments — independent of P, hoisted above the softmax
    bf16x8 vf0[4], vf1[4];
#pragma unroll
    for (int nt = 0; nt < 4; ++nt) {
      const int row = nt * 16 + l15;
      vf0[nt] = *(const bf16x8*)&Vs[cur][row * 64 + SW8(row, quad)];
      vf1[nt] = *(const bf16x8*)&Vs[cur][row * 64 + SW8(row, 4 + quad)];
    }

    // softmax: exp2 + sbfe/and mask, pack straight into PV A-frags
    bf16x8 pa0, pa1;
    {
      union { unsigned int w[4]; bf16x8 v; } A0, A1;
#pragma unroll
      for (int nt = 0; nt < 4; ++nt) {
        float p[4];
#pragma unroll
        for (int reg = 0; reg < 4; ++reg) {
          const unsigned int ws = (reg < 2) ? u_lo : u_hi;
          const int off = 16 * (reg & 1) + 8 * (nt >> 1) + (nt & 1);
          const float e = EXP2(sc[nt][reg]);
          const int m = SBFE1(ws, off);           // 0 or -1
          p[reg] = __uint_as_float(__float_as_uint(e) & (unsigned int)m);
        }
        Pp += (p[0] + p[1]) + (p[2] + p[3]);
        const unsigned int d0 = f2bf_pk(p[0], p[1]);
        const unsigned int d1 = f2bf_pk(p[2], p[3]);
        if (nt == 0)      { A0.w[0] = d0; A0.w[1] = d1; }
        else if (nt == 1) { A0.w[2] = d0; A0.w[3] = d1; }
        else if (nt == 2) { A1.w[0] = d0; A1.w[1] = d1; }
        else              { A1.w[2] = d0; A1.w[3] = d1; }
      }
      pa0 = A0.v; pa1 = A1.v;
    }

    // O += P @ V^T (P already in A-frag layout)
    __builtin_amdgcn_s_setprio(1);
#pragma unroll
    for (int nt = 0; nt < 4; ++nt) {
      accO[nt] = mfma16(pa0, vf0[nt], accO[nt]);
      accO[nt] = mfma16(pa1, vf1[nt], accO[nt]);
    }
    __builtin_amdgcn_s_setprio(0);
  }

  // Pp: lane (quad,l15) holds partial row-sum for q-row l15 over that quad's
  // tokens. Reduce over quads (lane^16, lane^32).
  Pp += __shfl_xor(Pp, 16);
  Pp += __shfl_xor(Pp, 32);
  Pp = 1.0f / (Pp + 1e-30f);
  // redistribute: epilogue needs inv-sum for q-row quad*4 + reg
  float Ppe[4];
#pragma unroll
  for (int reg = 0; reg < 4; ++reg)
    Ppe[reg] = __shfl(Pp, (quad << 4) | (quad * 4 + reg));

#pragma unroll
  for (int nt = 0; nt < 4; ++nt)
#pragma unroll
    for (int reg = 0; reg < 4; ++reg) {
      const int row = wave * 16 + quad * 4 + reg;
      ctx[(size_t)(b * S_ + qb + row) * D_ + h * HD_ + nt * 16 + l15] =
          f2bf(accO[nt][reg] * Ppe[reg]);
    }
}

// ---------------------------------------------------------------------------
extern "C" void kernel_launch(void* const* d_in, const int* in_sizes, int n_in,
                              void* d_out, int out_size, void* d_ws, size_t ws_size,
                              hipStream_t stream) {
  const float* x     = (const float*)d_in[0];
  const float* V     = (const float*)d_in[1];
  const float* Mm    = (const float*)d_in[2];
  const float* w_in  = (const float*)d_in[3];
  const float* b_in  = (const float*)d_in[4];
  const float* w_out = (const float*)d_in[5];
  const float* b_out = (const float*)d_in[6];
  float* out = (float*)d_out;                  // fp32 (verified R5)

  // workspace layout (ushort units)
  unsigned short* qk  = (unsigned short*)d_ws;          // 8M   [4096][2048]
  unsigned short* vt  = qk  + (size_t)8 * 1024 * 1024;  // 4M   [B][H][HD][S]
  unsigned short* ctx = vt  + (size_t)4 * 1024 * 1024;  // 4M   [4096][1024]
  unsigned short* xb  = ctx + (size_t)4 * 1024 * 1024;  // 4M   bf16(x)
  unsigned short* wb  = xb  + (size_t)4 * 1024 * 1024;  // 2M   bf16(w_in[0:2048])
  unsigned short* wob = wb  + (size_t)2 * 1024 * 1024;  // 1M   bf16(out_w)
  unsigned long long* mpk = (unsigned long long*)(wob + (size_t)1024 * 1024);

  // 0) fused prep: converts + ballot mask pack + V transpose (one dispatch)
  prep_kernel<<<5120, 256, 0, stream>>>(x, w_in, w_out, V, Mm,
                                        xb, wb, wob, vt, mpk);

  // 1) QK = x @ in_proj_w[0:2048]^T + b_in; Q cols pre-scaled by QSCALE
  //    64x128 tile BK=32, dbuf, XCD-swizzled (16x64 tiles)
  gemm_tile<64, 128><<<1024, 256, 0, stream>>>(
      xb, wb, b_in, qk, nullptr, 2048, D_, 1);

  // 2) fused masked-renorm attention -> ctx (bf16), XCD-swizzled 1D grid
  attn_kernel<<<1024, 256, 0, stream>>>(qk, vt, mpk, ctx);

  // 3) out = ctx @ out_w^T + out_b  (fp32 store to d_out)
  //    64x64 tile BK=32, dbuf, XCD-swizzled (16x64 tiles)
  gemm_tile<64, 64><<<1024, 256, 0, stream>>>(
      ctx, wob, b_out, nullptr, out, D_, D_, 0);
}